// Round 3
// baseline (317.915 us; speedup 1.0000x reference)
//
#include <hip/hip_runtime.h>
#include <math.h>

// FM forward: one 16-lane group per sample, float4 loads (256B coalesced per field).
__global__ __launch_bounds__(256) void fm_fwd_kernel(
    const int* __restrict__ user_ids,
    const int* __restrict__ item_ids,
    const int* __restrict__ meta_ids,     // [B,2] row-major
    const float* __restrict__ user_emb,   // [N_USERS,64]
    const float* __restrict__ item_emb,   // [N_ITEMS,64]
    const float* __restrict__ meta_emb0,  // [1000,64]
    const float* __restrict__ meta_emb1,  // [20000,64]
    const float* __restrict__ user_lin,   // [N_USERS]
    const float* __restrict__ item_lin,   // [N_ITEMS]
    const float* __restrict__ meta_lin0,  // [1000]
    const float* __restrict__ meta_lin1,  // [20000]
    float* __restrict__ out,              // [B]
    int B)
{
    const int tid    = blockIdx.x * blockDim.x + threadIdx.x;
    const int sample = tid >> 4;          // 16 lanes per sample
    const int sub    = tid & 15;
    if (sample >= B) return;

    const int uid = user_ids[sample];
    const int iid = item_ids[sample];
    const int m0  = meta_ids[sample * 2 + 0];
    const int m1  = meta_ids[sample * 2 + 1];

    const float4 a = *reinterpret_cast<const float4*>(user_emb  + (size_t)uid * 64 + sub * 4);
    const float4 b = *reinterpret_cast<const float4*>(item_emb  + (size_t)iid * 64 + sub * 4);
    const float4 c = *reinterpret_cast<const float4*>(meta_emb0 + (size_t)m0  * 64 + sub * 4);
    const float4 d = *reinterpret_cast<const float4*>(meta_emb1 + (size_t)m1  * 64 + sub * 4);

    float t = 0.f;
    #pragma unroll
    for (int j = 0; j < 4; ++j) {
        const float av = (&a.x)[j];
        const float bv = (&b.x)[j];
        const float cv = (&c.x)[j];
        const float dv = (&d.x)[j];
        const float sv = av + bv + cv + dv;
        t += sv * sv - (av * av + bv * bv + cv * cv + dv * dv);
    }

    // reduce t over the 16-lane group (xor masks < 16 stay within the group)
    t += __shfl_xor(t, 1);
    t += __shfl_xor(t, 2);
    t += __shfl_xor(t, 4);
    t += __shfl_xor(t, 8);

    if (sub == 0) {
        const float linear = user_lin[uid] + item_lin[iid] + meta_lin0[m0] + meta_lin1[m1];
        const float x = linear + 0.5f * t;
        out[sample] = 1.0f / (1.0f + expf(-x));
    }
}

extern "C" void kernel_launch(void* const* d_in, const int* in_sizes, int n_in,
                              void* d_out, int out_size, void* d_ws, size_t ws_size,
                              hipStream_t stream) {
    const int*   user_ids  = (const int*)  d_in[0];
    const int*   item_ids  = (const int*)  d_in[1];
    const int*   meta_ids  = (const int*)  d_in[2];
    const float* user_emb  = (const float*)d_in[3];
    const float* item_emb  = (const float*)d_in[4];
    const float* meta_emb0 = (const float*)d_in[5];
    const float* meta_emb1 = (const float*)d_in[6];
    const float* user_lin  = (const float*)d_in[7];
    const float* item_lin  = (const float*)d_in[8];
    const float* meta_lin0 = (const float*)d_in[9];
    const float* meta_lin1 = (const float*)d_in[10];
    float* out = (float*)d_out;

    const int B = in_sizes[0];
    const int threads = 256;
    const int total   = B * 16;                   // 16 lanes per sample
    const int blocks  = (total + threads - 1) / threads;

    fm_fwd_kernel<<<blocks, threads, 0, stream>>>(
        user_ids, item_ids, meta_ids,
        user_emb, item_emb, meta_emb0, meta_emb1,
        user_lin, item_lin, meta_lin0, meta_lin1,
        out, B);
}